// Round 7
// baseline (424.616 us; speedup 1.0000x reference)
//
#include <hip/hip_runtime.h>

#define TT   1024
#define NW   34          // 32-col dirs records per band (format unchanged)
#define NWP  17          // 64-step phases per wave
#define NPH  (NWP + 14)  // barrier pipeline phases: NWP + 2*(8 waves - 1)
#define FINF 1e30f

template<bool A> struct BoolC { static constexpr bool value = A; };

// dirs layout (bit format as baseline, keyed by 64-row band):
//   uint2 {ne2_mask, diag_mask} at ((b*16+bi)*NW + T)*64 + rr
//   bit k of record T = col 32T - o + k, o = skew lane of row rr:
//   o = (bi&1)*32 + (rr>>1)  [8 waves x 128 rows, 2 rows/lane, slope-1]
// ne2: dir != left. diag: dir == diag (first-min argmin).
// Each 64-step phase P emits records T=2P and T=2P+1.

// DPP wave_shr:1: dest lane n = src lane n-1; lane 0 (invalid source, with
// bound_ctrl=false) keeps OLD -> pass the mailbox value as old and the
// boundary handoff for lane 0 costs ZERO extra instructions.
__device__ __forceinline__ float dpp_shr1_old(float oldv, float x) {
    return __int_as_float(__builtin_amdgcn_update_dpp(
        __float_as_int(oldv), __float_as_int(x), 0x138, 0xF, 0xF, false));
}

// ---------------- K1: forward DP, 1 batch/block, 8 waves, barrier pipeline --
// Wave w owns rows 128w..128w+127; lane L owns rows 128w+2L, +2L+1. Slope-1
// skew: at step s lane L computes col s-L for its 2 rows.
// 64-step phases, lag-2 schedule: wave w runs phase P = G - 2w at barrier
// phase G. Producer w-1 has completed phase P+1 at phase start -> published
// boundary cols <= 64P+64, exactly covering this phase's needs (last DPP
// old-value = col 64P+64). Loads hoisted per 32-step half; bndB issued
// before computeA so its latency hides under compute (in-order LDS).
// dirs stores deferred one phase. ACT peel only P==0 (covers s<64).
__global__ __launch_bounds__(512) void dtw_forward(
    const float* __restrict__ preds,
    const float* __restrict__ targs,
    uint2* __restrict__ dirs)
{
    __shared__ float2 qsh[TT];
    __shared__ float  mbox[7][TT];

    const int tid  = threadIdx.x;
    const int w    = tid >> 6;
    const int lane = tid & 63;
    const int b    = blockIdx.x;

    for (int k = tid; k < TT; k += 512) {
        float4 t4 = ((const float4*)targs)[(size_t)b * TT + k];
        qsh[k] = make_float2(t4.x, t4.y);
    }
    for (int k = tid; k < 7 * TT; k += 512) ((float*)mbox)[k] = FINF;

    float px0, py0, px1, py1;
    {
        const int row0 = w * 128 + 2 * lane;
        float4 pv = ((const float4*)preds)[(size_t)b * TT + row0];
        px0 = pv.x; py0 = pv.y;
        float4 pw = ((const float4*)preds)[(size_t)b * TT + row0 + 1];
        px1 = pw.x; py1 = pw.y;
    }
    __syncthreads();

    const float* src = (w > 0) ? mbox[w - 1] : nullptr;
    float*       dst = (w < 7) ? mbox[w]     : nullptr;

    float cur0 = FINF, cur1 = FINF, uprev = FINF, ucur = FINF;
    unsigned pA0 = 0, pA1 = 0, pA2 = 0, pA3 = 0;   // deferred record 2P
    unsigned pB0 = 0, pB1 = 0, pB2 = 0, pB3 = 0;   // deferred record 2P+1
    int pP = -1;

    const int bi  = 2 * w + (lane >> 5);     // 64-row band index (within batch)
    const int rr0 = 2 * (lane & 31);         // row within band
    const bool pub = (lane == 63) && (w < 7);

    for (int G = 0; G < NPH; ++G) {
        // ---- deferred dirs stores for the previous phase (post-barrier) ----
        if (pP >= 0) {
            const size_t base = (size_t)((b * 16 + bi) * NW + 2 * pP) * 64 + rr0;
            *(uint4*)&dirs[base] = make_uint4(
                __builtin_bitreverse32(pA0), __builtin_bitreverse32(pA1),
                __builtin_bitreverse32(pA2), __builtin_bitreverse32(pA3));
            *(uint4*)&dirs[base + 64] = make_uint4(
                __builtin_bitreverse32(pB0), __builtin_bitreverse32(pB1),
                __builtin_bitreverse32(pB2), __builtin_bitreverse32(pB3));
            pP = -1;
        }
        const int P = G - 2 * w;             // wave-uniform phase index
        if ((unsigned)P < (unsigned)NWP) {
            const int s0 = 64 * P;
            // ---- boundary loads for both halves (w-uniform branches) ----
            float bndA[33], bndB[33];
#pragma unroll
            for (int k = 0; k < 33; ++k) { bndA[k] = FINF; bndB[k] = FINF; }
            if (w > 0) {
                if (P <= 14) {
#pragma unroll
                    for (int k = 0; k < 33; ++k) bndA[k] = src[s0 + k];
#pragma unroll
                    for (int k = 0; k < 33; ++k) bndB[k] = src[s0 + 32 + k];
                } else {
#pragma unroll
                    for (int k = 0; k < 33; ++k) {
                        if (s0 + k < TT)      bndA[k] = src[s0 + k];
                        if (s0 + 32 + k < TT) bndB[k] = src[s0 + 32 + k];
                    }
                }
            }
            // ---- q loads, half A (offset-folded when no wrap possible) ----
            float qxA[32], qyA[32];
            if (P >= 1 && P <= 15) {
                const float2* qp = &qsh[s0 - lane];
#pragma unroll
                for (int k = 0; k < 32; ++k) { qxA[k] = qp[k].x; qyA[k] = qp[k].y; }
            } else {
#pragma unroll
                for (int k = 0; k < 32; ++k) {
                    float2 v = qsh[(s0 + k - lane) & (TT - 1)];
                    qxA[k] = v.x; qyA[k] = v.y;
                }
            }
            if (P == 0) ucur = bndA[0];   // first-step u: src[0] (w>0) / FINF
            unsigned au0 = 0, ad0 = 0, au1 = 0, ad1 = 0;
            float bq[32];
            auto half = [&](const float* bnd, const float* qx, const float* qy,
                            int sbase, auto actc) {
                constexpr bool ACT = decltype(actc)::value;
#pragma unroll
                for (int k2 = 0; k2 < 32; ++k2) {
                    const float dx0 = px0 - qx[k2], dy0 = py0 - qy[k2];
                    const float d0 = __builtin_amdgcn_sqrtf(dx0 * dx0 + dy0 * dy0);
                    const float dx1 = px1 - qx[k2], dy1 = py1 - qy[k2];
                    const float d1 = __builtin_amdgcn_sqrtf(dx1 * dx1 + dy1 * dy1);

                    const float u = ucur;
                    // row0: cd=uprev, cu=u, cl=cur0  (min3 + eq-argmin)
                    float ba0 = fminf(fminf(u, cur0), uprev);
                    const unsigned bd0 = (uprev == ba0) ? 1u : 0u;
                    const unsigned bu0 = ((u <= cur0) ? 1u : 0u) | bd0;
                    if constexpr (ACT) ba0 = (ba0 > 9e29f) ? 0.0f : ba0;
                    const float v0 = d0 + ba0;
                    // row1: cd=cur0, cu=v0, cl=cur1
                    const float ba1 = fminf(fminf(v0, cur1), cur0);
                    const unsigned bd1 = (cur0 == ba1) ? 1u : 0u;
                    const unsigned bu1 = ((v0 <= cur1) ? 1u : 0u) | bd1;
                    const float v1 = d1 + ba1;

                    au0 = au0 + au0 + bu0;  ad0 = ad0 + ad0 + bd0;
                    au1 = au1 + au1 + bu1;  ad1 = ad1 + ad1 + bd1;

                    if constexpr (ACT) {
                        const bool act = (lane <= sbase + k2);
                        cur0 = act ? v0 : cur0;
                        cur1 = act ? v1 : cur1;
                    } else {
                        cur0 = v0; cur1 = v1;
                    }
                    uprev = u;
                    bq[k2] = cur1;
                    // next step's u: lane0 <- boundary col s+1, lanes>0 <- shift
                    ucur = dpp_shr1_old(bnd[k2 + 1], cur1);
                }
            };
            // ---- half A ----
            if (P == 0) half(bndA, qxA, qyA, 0, BoolC<true>{});
            else        half(bndA, qxA, qyA, 0, BoolC<false>{});
            pA0 = au0; pA1 = ad0; pA2 = au1; pA3 = ad1;
            au0 = ad0 = au1 = ad1 = 0u;
            if (pub) {
#pragma unroll
                for (int k2 = 0; k2 < 32; ++k2) {
                    const int c = s0 + k2 - 63;
                    if ((unsigned)c < 1024u) dst[c] = bq[k2];
                }
            }
            // ---- q loads, half B ----
            float qxB[32], qyB[32];
            if (P >= 1 && P <= 15) {
                const float2* qp = &qsh[s0 + 32 - lane];
#pragma unroll
                for (int k = 0; k < 32; ++k) { qxB[k] = qp[k].x; qyB[k] = qp[k].y; }
            } else {
#pragma unroll
                for (int k = 0; k < 32; ++k) {
                    float2 v = qsh[(s0 + 32 + k - lane) & (TT - 1)];
                    qxB[k] = v.x; qyB[k] = v.y;
                }
            }
            // ---- half B ----
            if (P == 0) half(bndB, qxB, qyB, 32, BoolC<true>{});
            else        half(bndB, qxB, qyB, 32, BoolC<false>{});
            pB0 = au0; pB1 = ad0; pB2 = au1; pB3 = ad1;
            if (pub) {
#pragma unroll
                for (int k2 = 0; k2 < 32; ++k2) {
                    const int c = s0 + 32 + k2 - 63;
                    if ((unsigned)c < 1024u) dst[c] = bq[k2];
                }
            }
            pP = P;
        }
        __syncthreads();   // phase barrier (uniform across the block)
    }
    // flush the final phase's dirs
    if (pP >= 0) {
        const size_t base = (size_t)((b * 16 + bi) * NW + 2 * pP) * 64 + rr0;
        *(uint4*)&dirs[base] = make_uint4(
            __builtin_bitreverse32(pA0), __builtin_bitreverse32(pA1),
            __builtin_bitreverse32(pA2), __builtin_bitreverse32(pA3));
        *(uint4*)&dirs[base + 64] = make_uint4(
            __builtin_bitreverse32(pB0), __builtin_bitreverse32(pB1),
            __builtin_bitreverse32(pB2), __builtin_bitreverse32(pB3));
    }
}

// ---------------- K2: exit-only per-band walk (no loss) ----------------
__global__ __launch_bounds__(1024) void dtw_exits(
    const uint2* __restrict__ dirs,
    unsigned short* __restrict__ exitc)
{
    __shared__ uint2 raw[NW * 64];
    __shared__ unsigned nebit[64][32];
    __shared__ unsigned dgbit[64][32];

    const int tid = threadIdx.x;
    const int b = blockIdx.x >> 4, bi = blockIdx.x & 15;

    for (int i = tid; i < NW * 64; i += 1024)
        raw[i] = dirs[(size_t)(b * 16 + bi) * (NW * 64) + i];
    __syncthreads();
    for (int i = tid; i < 64 * 32; i += 1024) {
        const int rr = i >> 5, u = i & 31;
        const int o  = ((bi & 1) << 5) + (rr >> 1);   // slope-1, 2 rows/lane
        const int T0 = u + (o >> 5), sh = o & 31;
        uint2 A  = raw[T0 * 64 + rr];
        uint2 Bv = raw[(T0 + 1) * 64 + rr];
        nebit[rr][u] = sh ? ((A.x >> sh) | (Bv.x << (32 - sh))) : A.x;
        dgbit[rr][u] = sh ? ((A.y >> sh) | (Bv.y << (32 - sh))) : A.y;
    }
    __syncthreads();

    int j = tid;
    for (int rr = 63; rr >= 0; --rr) {
        if (bi == 0 && rr == 0) { j = 0; break; }
        int u = j >> 5, m = j & 31;
        unsigned wv = nebit[rr][u] << (31 - m);
        while (wv == 0u && u > 0) { --u; wv = nebit[rr][u]; m = 31; }
        const int j2 = (wv == 0u) ? 0 : ((u << 5) + m - __builtin_clz(wv));
        const int diag = (int)((dgbit[rr][j2 >> 5] >> (j2 & 31)) & 1u);
        j = j2 - diag;
        if (j < 0) j = 0;   // safety net (unreachable on correct dirs)
    }
    exitc[((size_t)(b * 16 + bi) << 10) + tid] = (unsigned short)j;
}

// ---------------- K3: loss replay (stitch folded in) ----------------
__global__ __launch_bounds__(64) void dtw_loss(
    const float* __restrict__ preds,
    const float* __restrict__ targs,
    const float* __restrict__ subcoef,
    const uint2* __restrict__ dirs,
    const unsigned short* __restrict__ exitc,
    float* __restrict__ out)
{
    __shared__ uint2 raw[NW * 64];
    __shared__ unsigned nebit[64][32];
    __shared__ unsigned dgbit[64][32];
    __shared__ float2 qsh[TT];
    __shared__ float2 psh[64];
    __shared__ unsigned recs[160];

    const int lane = threadIdx.x;
    const int b = blockIdx.x >> 4, bi = blockIdx.x & 15;

    for (int i = lane; i < NW * 64; i += 64)
        raw[i] = dirs[(size_t)(b * 16 + bi) * (NW * 64) + i];
    for (int k = lane; k < TT; k += 64) {
        float4 t4 = ((const float4*)targs)[(size_t)b * TT + k];
        qsh[k] = make_float2(t4.x, t4.y);
    }
    {
        float4 p4 = ((const float4*)preds)[(size_t)b * TT + bi * 64 + lane];
        psh[lane] = make_float2(p4.x, p4.y);
    }
    __syncthreads();
    for (int i = lane; i < 64 * 32; i += 64) {
        const int rr = i >> 5, u = i & 31;
        const int o  = ((bi & 1) << 5) + (rr >> 1);   // slope-1, 2 rows/lane
        const int T0 = u + (o >> 5), sh = o & 31;
        uint2 A  = raw[T0 * 64 + rr];
        uint2 Bv = raw[(T0 + 1) * 64 + rr];
        nebit[rr][u] = sh ? ((A.x >> sh) | (Bv.x << (32 - sh))) : A.x;
        dgbit[rr][u] = sh ? ((A.y >> sh) | (Bv.y << (32 - sh))) : A.y;
    }

    // entry col for this band: fold of exitc over bands 15..bi+1 (K3 inlined;
    // broadcast same-address loads, <=15 dependent L2 hits)
    int j = TT - 1;
    for (int k = 15; k > bi; --k)
        j = exitc[((size_t)(b * 16 + k) << 10) + j];
    __syncthreads();

    // wave-redundant replay; lane 0 records <=32-col span chunks
    int nrec = 0;
    for (int rr = 63; rr >= 0; --rr) {
        int j2;
        if (bi == 0 && rr == 0) j2 = 0;
        else {
            int u = j >> 5, m = j & 31;
            unsigned wv = nebit[rr][u] << (31 - m);
            while (wv == 0u && u > 0) { --u; wv = nebit[rr][u]; m = 31; }
            j2 = (wv == 0u) ? 0 : ((u << 5) + m - __builtin_clz(wv));
        }
        int c = j;
        for (;;) {
            int cl = (c - 31 > j2) ? (c - 31) : j2;
            if (lane == 0)
                recs[nrec] = ((unsigned)rr << 20) | ((unsigned)cl << 10) | (unsigned)c;
            ++nrec;
            if (cl == j2) break;
            c = cl - 1;
        }
        if (bi == 0 && rr == 0) j = 0;
        else {
            const int diag = (int)((dgbit[rr][j2 >> 5] >> (j2 & 31)) & 1u);
            j = j2 - diag;
            if (j < 0) j = 0;   // safety net (unreachable on correct dirs)
        }
    }
    __syncthreads();

    const float sc0 = subcoef[0], sc1 = subcoef[1];
    float acc = 0.0f;
    for (int k = lane; k < nrec; k += 64) {
        unsigned rec = recs[k];
        int rr = (int)(rec >> 20), cl = (int)((rec >> 10) & 1023u), ch = (int)(rec & 1023u);
        float2 p = psh[rr];
        for (int c = cl; c <= ch; ++c) {
            float2 q = qsh[c];
            acc += fabsf(p.x - q.x) * sc0 + fabsf(p.y - q.y) * sc1;
        }
    }
    for (int o = 32; o; o >>= 1) acc += __shfl_down(acc, o);
    if (lane == 0) atomicAdd(out, acc);
}

extern "C" void kernel_launch(void* const* d_in, const int* in_sizes, int n_in,
                              void* d_out, int out_size, void* d_ws, size_t ws_size,
                              hipStream_t stream)
{
    const float* preds   = (const float*)d_in[0];
    const float* targs   = (const float*)d_in[1];
    const float* subcoef = (const float*)d_in[2];
    float* out = (float*)d_out;

    const int B = in_sizes[0] / (TT * 4);

    const size_t dirsBytes = (size_t)B * 16 * NW * 64 * sizeof(uint2);        // ~17.8 MB
    uint2* dirs = (uint2*)d_ws;
    unsigned short* exitc = (unsigned short*)((char*)d_ws + dirsBytes);       // 2 MB

    hipMemsetAsync(out, 0, sizeof(float), stream);
    dtw_forward<<<dim3(B), dim3(512), 0, stream>>>(preds, targs, dirs);
    dtw_exits<<<dim3(B * 16), dim3(1024), 0, stream>>>(dirs, exitc);
    dtw_loss<<<dim3(B * 16), dim3(64), 0, stream>>>(preds, targs, subcoef, dirs, exitc, out);
}

// Round 8
// 419.170 us; speedup vs baseline: 1.0130x; 1.0130x over previous
//
#include <hip/hip_runtime.h>

#define TT   1024
#define NW   34          // 32-col dirs records per band (format unchanged)
#define NWP  17          // 64-step phases (window pairs) per wave
#define NPH  (NWP + 14)  // barrier pipeline phases: NWP + 2*(8 waves - 1)
#define FINF 1e30f

template<bool A> struct BoolC { static constexpr bool value = A; };

// dirs layout (bit format as baseline, keyed by 64-row band):
//   uint2 {ne2_mask, diag_mask} at ((b*16+bi)*NW + T)*64 + rr
//   bit k of record T = col 32T - o + k, o = skew lane of row rr:
//   o = (bi&1)*32 + (rr>>1)  [8 waves x 128 rows, 2 rows/lane, slope-1]
// ne2: dir != left. diag: dir == diag (first-min argmin).
// Each barrier phase P executes windows T=2P and T=2P+1 SEQUENTIALLY with the
// SAME register arrays (r7's spill bug: both windows' arrays live at once).

// DPP wave_shr:1: dest lane n = src lane n-1; lane 0 (invalid source, with
// bound_ctrl=false) keeps OLD -> pass the mailbox value as old and the
// boundary handoff for lane 0 costs ZERO extra instructions.
__device__ __forceinline__ float dpp_shr1_old(float oldv, float x) {
    return __int_as_float(__builtin_amdgcn_update_dpp(
        __float_as_int(oldv), __float_as_int(x), 0x138, 0xF, 0xF, false));
}

// ---------------- K1: forward DP, 1 batch/block, 8 waves, barrier pipeline --
// Wave w owns rows 128w..128w+127; lane L owns rows 128w+2L, +2L+1. Slope-1
// skew: at step s lane L computes col s-L for its 2 rows.
// Pair schedule, lag-2: wave w runs pair P = G - 2w at barrier phase G.
// Producer w-1 has completed pair P+1 at phase start -> published boundary
// cols <= 64P+64, exactly covering this pair's needs (last DPP old value =
// col 64P+64). Loads hoisted per 32-step window; dirs stores deferred one
// phase (both records). ACT peel only P==0 (covers s<64). Tail windows
// (T>=32) compute self-contained garbage for cols>=1024 (never read by K2/K4).
__global__ __launch_bounds__(512) void dtw_forward(
    const float* __restrict__ preds,
    const float* __restrict__ targs,
    uint2* __restrict__ dirs)
{
    __shared__ float2 qsh[TT];
    __shared__ float  mbox[7][TT];

    const int tid  = threadIdx.x;
    const int w    = tid >> 6;
    const int lane = tid & 63;
    const int b    = blockIdx.x;

    for (int k = tid; k < TT; k += 512) {
        float4 t4 = ((const float4*)targs)[(size_t)b * TT + k];
        qsh[k] = make_float2(t4.x, t4.y);
    }
    for (int k = tid; k < 7 * TT; k += 512) ((float*)mbox)[k] = FINF;

    float px0, py0, px1, py1;
    {
        const int row0 = w * 128 + 2 * lane;
        float4 pv = ((const float4*)preds)[(size_t)b * TT + row0];
        px0 = pv.x; py0 = pv.y;
        float4 pw = ((const float4*)preds)[(size_t)b * TT + row0 + 1];
        px1 = pw.x; py1 = pw.y;
    }
    __syncthreads();

    const float* src = (w > 0) ? mbox[w - 1] : nullptr;
    float*       dst = (w < 7) ? mbox[w]     : nullptr;

    float cur0 = FINF, cur1 = FINF, uprev = FINF, ucur = FINF;
    unsigned pA0 = 0, pA1 = 0, pA2 = 0, pA3 = 0;   // deferred record 2P
    unsigned pB0 = 0, pB1 = 0, pB2 = 0, pB3 = 0;   // deferred record 2P+1
    int pP = -1;

    const int bi  = 2 * w + (lane >> 5);     // 64-row band index (within batch)
    const int rr0 = 2 * (lane & 31);         // row within band
    const bool pub = (lane == 63) && (w < 7);

    // one 32-step window, r6's proven body (loads hoisted, straight unroll)
    auto runWindow = [&](int T, unsigned& o0, unsigned& o1,
                         unsigned& o2, unsigned& o3) {
        const int s0 = 32 * T;
        float bnd[33];
#pragma unroll
        for (int k = 0; k < 33; ++k) bnd[k] = FINF;
        if (w > 0 && s0 < TT) {
            if (T <= 30) {
#pragma unroll
                for (int k = 0; k < 33; ++k) bnd[k] = src[s0 + k];
            } else {
#pragma unroll
                for (int k = 0; k < 33; ++k)
                    if (s0 + k < TT) bnd[k] = src[s0 + k];
            }
        }
        if (T == 0) ucur = bnd[0];   // first-step u: src[0] (w>0) / FINF (w=0)
        float qx[32], qy[32];
        if (T >= 2 && T <= 31) {     // no wrap possible: offset-folded reads
            const float2* qp = &qsh[s0 - lane];
#pragma unroll
            for (int k = 0; k < 32; ++k) { qx[k] = qp[k].x; qy[k] = qp[k].y; }
        } else {
#pragma unroll
            for (int k = 0; k < 32; ++k) {
                float2 v = qsh[(s0 + k - lane) & (TT - 1)];
                qx[k] = v.x; qy[k] = v.y;
            }
        }
        unsigned au0 = 0, ad0 = 0, au1 = 0, ad1 = 0;
        float bq[32];
        auto body = [&](auto actc) {
            constexpr bool ACT = decltype(actc)::value;
#pragma unroll
            for (int k2 = 0; k2 < 32; ++k2) {
                const float dx0 = px0 - qx[k2], dy0 = py0 - qy[k2];
                const float d0 = __builtin_amdgcn_sqrtf(dx0 * dx0 + dy0 * dy0);
                const float dx1 = px1 - qx[k2], dy1 = py1 - qy[k2];
                const float d1 = __builtin_amdgcn_sqrtf(dx1 * dx1 + dy1 * dy1);

                const float u = ucur;
                // row0: cd=uprev, cu=u, cl=cur0  (min3 + eq-argmin)
                float ba0 = fminf(fminf(u, cur0), uprev);
                const unsigned bd0 = (uprev == ba0) ? 1u : 0u;
                const unsigned bu0 = ((u <= cur0) ? 1u : 0u) | bd0;
                if constexpr (ACT) ba0 = (ba0 > 9e29f) ? 0.0f : ba0;
                const float v0 = d0 + ba0;
                // row1: cd=cur0, cu=v0, cl=cur1
                const float ba1 = fminf(fminf(v0, cur1), cur0);
                const unsigned bd1 = (cur0 == ba1) ? 1u : 0u;
                const unsigned bu1 = ((v0 <= cur1) ? 1u : 0u) | bd1;
                const float v1 = d1 + ba1;

                au0 = au0 + au0 + bu0;  ad0 = ad0 + ad0 + bd0;
                au1 = au1 + au1 + bu1;  ad1 = ad1 + ad1 + bd1;

                if constexpr (ACT) {
                    const bool act = (lane <= s0 + k2);
                    cur0 = act ? v0 : cur0;
                    cur1 = act ? v1 : cur1;
                } else {
                    cur0 = v0; cur1 = v1;
                }
                uprev = u;
                bq[k2] = cur1;
                // next step's u: lane0 <- boundary col s+1, lanes>0 <- shift
                ucur = dpp_shr1_old(bnd[k2 + 1], cur1);
            }
        };
        if (T < 2) body(BoolC<true>{}); else body(BoolC<false>{});

        // batched boundary publish (plain LDS; closing barrier orders it)
        if (pub) {
#pragma unroll
            for (int k2 = 0; k2 < 32; ++k2) {
                const int c = s0 + k2 - 63;
                if ((unsigned)c < 1024u) dst[c] = bq[k2];
            }
        }
        o0 = au0; o1 = ad0; o2 = au1; o3 = ad1;
    };

    for (int G = 0; G < NPH; ++G) {
        // ---- deferred dirs stores for the previous pair (post-barrier) ----
        if (pP >= 0) {
            const size_t base = (size_t)((b * 16 + bi) * NW + 2 * pP) * 64 + rr0;
            *(uint4*)&dirs[base] = make_uint4(
                __builtin_bitreverse32(pA0), __builtin_bitreverse32(pA1),
                __builtin_bitreverse32(pA2), __builtin_bitreverse32(pA3));
            *(uint4*)&dirs[base + 64] = make_uint4(
                __builtin_bitreverse32(pB0), __builtin_bitreverse32(pB1),
                __builtin_bitreverse32(pB2), __builtin_bitreverse32(pB3));
            pP = -1;
        }
        const int P = G - 2 * w;             // wave-uniform pair index
        if ((unsigned)P < (unsigned)NWP) {
            runWindow(2 * P,     pA0, pA1, pA2, pA3);
            runWindow(2 * P + 1, pB0, pB1, pB2, pB3);
            pP = P;
        }
        __syncthreads();   // phase barrier (uniform across the block)
    }
    // flush the final pair's dirs
    if (pP >= 0) {
        const size_t base = (size_t)((b * 16 + bi) * NW + 2 * pP) * 64 + rr0;
        *(uint4*)&dirs[base] = make_uint4(
            __builtin_bitreverse32(pA0), __builtin_bitreverse32(pA1),
            __builtin_bitreverse32(pA2), __builtin_bitreverse32(pA3));
        *(uint4*)&dirs[base + 64] = make_uint4(
            __builtin_bitreverse32(pB0), __builtin_bitreverse32(pB1),
            __builtin_bitreverse32(pB2), __builtin_bitreverse32(pB3));
    }
}

// ---------------- K2: exit-only per-band walk (no loss) ----------------
__global__ __launch_bounds__(1024) void dtw_exits(
    const uint2* __restrict__ dirs,
    unsigned short* __restrict__ exitc)
{
    __shared__ uint2 raw[NW * 64];
    __shared__ unsigned nebit[64][32];
    __shared__ unsigned dgbit[64][32];

    const int tid = threadIdx.x;
    const int b = blockIdx.x >> 4, bi = blockIdx.x & 15;

    for (int i = tid; i < NW * 64; i += 1024)
        raw[i] = dirs[(size_t)(b * 16 + bi) * (NW * 64) + i];
    __syncthreads();
    for (int i = tid; i < 64 * 32; i += 1024) {
        const int rr = i >> 5, u = i & 31;
        const int o  = ((bi & 1) << 5) + (rr >> 1);   // slope-1, 2 rows/lane
        const int T0 = u + (o >> 5), sh = o & 31;
        uint2 A  = raw[T0 * 64 + rr];
        uint2 Bv = raw[(T0 + 1) * 64 + rr];
        nebit[rr][u] = sh ? ((A.x >> sh) | (Bv.x << (32 - sh))) : A.x;
        dgbit[rr][u] = sh ? ((A.y >> sh) | (Bv.y << (32 - sh))) : A.y;
    }
    __syncthreads();

    int j = tid;
    for (int rr = 63; rr >= 0; --rr) {
        if (bi == 0 && rr == 0) { j = 0; break; }
        int u = j >> 5, m = j & 31;
        unsigned wv = nebit[rr][u] << (31 - m);
        while (wv == 0u && u > 0) { --u; wv = nebit[rr][u]; m = 31; }
        const int j2 = (wv == 0u) ? 0 : ((u << 5) + m - __builtin_clz(wv));
        const int diag = (int)((dgbit[rr][j2 >> 5] >> (j2 & 31)) & 1u);
        j = j2 - diag;
        if (j < 0) j = 0;   // safety net (unreachable on correct dirs)
    }
    exitc[((size_t)(b * 16 + bi) << 10) + tid] = (unsigned short)j;
}

// ---------------- K3: loss replay (stitch folded in) ----------------
__global__ __launch_bounds__(64) void dtw_loss(
    const float* __restrict__ preds,
    const float* __restrict__ targs,
    const float* __restrict__ subcoef,
    const uint2* __restrict__ dirs,
    const unsigned short* __restrict__ exitc,
    float* __restrict__ out)
{
    __shared__ uint2 raw[NW * 64];
    __shared__ unsigned nebit[64][32];
    __shared__ unsigned dgbit[64][32];
    __shared__ float2 qsh[TT];
    __shared__ float2 psh[64];
    __shared__ unsigned recs[160];

    const int lane = threadIdx.x;
    const int b = blockIdx.x >> 4, bi = blockIdx.x & 15;

    for (int i = lane; i < NW * 64; i += 64)
        raw[i] = dirs[(size_t)(b * 16 + bi) * (NW * 64) + i];
    for (int k = lane; k < TT; k += 64) {
        float4 t4 = ((const float4*)targs)[(size_t)b * TT + k];
        qsh[k] = make_float2(t4.x, t4.y);
    }
    {
        float4 p4 = ((const float4*)preds)[(size_t)b * TT + bi * 64 + lane];
        psh[lane] = make_float2(p4.x, p4.y);
    }
    __syncthreads();
    for (int i = lane; i < 64 * 32; i += 64) {
        const int rr = i >> 5, u = i & 31;
        const int o  = ((bi & 1) << 5) + (rr >> 1);   // slope-1, 2 rows/lane
        const int T0 = u + (o >> 5), sh = o & 31;
        uint2 A  = raw[T0 * 64 + rr];
        uint2 Bv = raw[(T0 + 1) * 64 + rr];
        nebit[rr][u] = sh ? ((A.x >> sh) | (Bv.x << (32 - sh))) : A.x;
        dgbit[rr][u] = sh ? ((A.y >> sh) | (Bv.y << (32 - sh))) : A.y;
    }

    // entry col for this band: fold of exitc over bands 15..bi+1 (K3 inlined;
    // broadcast same-address loads, <=15 dependent L2 hits)
    int j = TT - 1;
    for (int k = 15; k > bi; --k)
        j = exitc[((size_t)(b * 16 + k) << 10) + j];
    __syncthreads();

    // wave-redundant replay; lane 0 records <=32-col span chunks
    int nrec = 0;
    for (int rr = 63; rr >= 0; --rr) {
        int j2;
        if (bi == 0 && rr == 0) j2 = 0;
        else {
            int u = j >> 5, m = j & 31;
            unsigned wv = nebit[rr][u] << (31 - m);
            while (wv == 0u && u > 0) { --u; wv = nebit[rr][u]; m = 31; }
            j2 = (wv == 0u) ? 0 : ((u << 5) + m - __builtin_clz(wv));
        }
        int c = j;
        for (;;) {
            int cl = (c - 31 > j2) ? (c - 31) : j2;
            if (lane == 0)
                recs[nrec] = ((unsigned)rr << 20) | ((unsigned)cl << 10) | (unsigned)c;
            ++nrec;
            if (cl == j2) break;
            c = cl - 1;
        }
        if (bi == 0 && rr == 0) j = 0;
        else {
            const int diag = (int)((dgbit[rr][j2 >> 5] >> (j2 & 31)) & 1u);
            j = j2 - diag;
            if (j < 0) j = 0;   // safety net (unreachable on correct dirs)
        }
    }
    __syncthreads();

    const float sc0 = subcoef[0], sc1 = subcoef[1];
    float acc = 0.0f;
    for (int k = lane; k < nrec; k += 64) {
        unsigned rec = recs[k];
        int rr = (int)(rec >> 20), cl = (int)((rec >> 10) & 1023u), ch = (int)(rec & 1023u);
        float2 p = psh[rr];
        for (int c = cl; c <= ch; ++c) {
            float2 q = qsh[c];
            acc += fabsf(p.x - q.x) * sc0 + fabsf(p.y - q.y) * sc1;
        }
    }
    for (int o = 32; o; o >>= 1) acc += __shfl_down(acc, o);
    if (lane == 0) atomicAdd(out, acc);
}

extern "C" void kernel_launch(void* const* d_in, const int* in_sizes, int n_in,
                              void* d_out, int out_size, void* d_ws, size_t ws_size,
                              hipStream_t stream)
{
    const float* preds   = (const float*)d_in[0];
    const float* targs   = (const float*)d_in[1];
    const float* subcoef = (const float*)d_in[2];
    float* out = (float*)d_out;

    const int B = in_sizes[0] / (TT * 4);

    const size_t dirsBytes = (size_t)B * 16 * NW * 64 * sizeof(uint2);        // ~17.8 MB
    uint2* dirs = (uint2*)d_ws;
    unsigned short* exitc = (unsigned short*)((char*)d_ws + dirsBytes);       // 2 MB

    hipMemsetAsync(out, 0, sizeof(float), stream);
    dtw_forward<<<dim3(B), dim3(512), 0, stream>>>(preds, targs, dirs);
    dtw_exits<<<dim3(B * 16), dim3(1024), 0, stream>>>(dirs, exitc);
    dtw_loss<<<dim3(B * 16), dim3(64), 0, stream>>>(preds, targs, subcoef, dirs, exitc, out);
}

// Round 9
// 409.713 us; speedup vs baseline: 1.0364x; 1.0231x over previous
//
#include <hip/hip_runtime.h>

#define TT   1024
#define NW   34          // 32-step windows; slope-1 skew offset up to 63
#define NPH  (NW + 21)   // barrier pipeline phases: NW + 3*(8 waves - 1)
#define FINF 1e30f

template<bool A> struct BoolC { static constexpr bool value = A; };

// dirs layout (bit format as baseline, keyed by 64-row band):
//   uint2 {ne2_mask, diag_mask} at ((b*16+bi)*NW + T)*64 + rr
//   bit k of window T = col 32T - o + k, o = skew lane of row rr:
//   o = (bi&1)*32 + (rr>>1)  [8 waves x 128 rows, 2 rows/lane, slope-1]
// ne2: dir != left. diag: dir == diag (first-min argmin).

// DPP wave_shr:1: dest lane n = src lane n-1; lane 0 (invalid source, with
// bound_ctrl=false) keeps OLD -> pass the mailbox value as old and the
// boundary handoff for lane 0 costs ZERO extra instructions.
__device__ __forceinline__ float dpp_shr1_old(float oldv, float x) {
    return __int_as_float(__builtin_amdgcn_update_dpp(
        __float_as_int(oldv), __float_as_int(x), 0x138, 0xF, 0xF, false));
}

// ---------------- K1: forward DP, 1 batch/worker-block, 8 waves ------------
// CU-SPREAD: grid = 4*B; only blockIdx%4==0 works (batch = blockIdx>>2).
// Rationale: 512-thread/36.8kB blocks can legally co-reside 2/CU; counters
// (VALUBusy 12.1% global ~= 97% if 32 CUs active) say the dispatcher packs
// them -> VALU-issue-saturated. Early-exit padding blocks force workers onto
// distinct CUs. Body identical to the verified r6 kernel (233us, 0 conflicts).
__global__ __launch_bounds__(512) void dtw_forward(
    const float* __restrict__ preds,
    const float* __restrict__ targs,
    uint2* __restrict__ dirs)
{
    __shared__ float2 qsh[TT];
    __shared__ float  mbox[7][TT];

    if (blockIdx.x & 3) return;              // spreader no-op block
    const int b = blockIdx.x >> 2;

    const int tid  = threadIdx.x;
    const int w    = tid >> 6;
    const int lane = tid & 63;

    for (int k = tid; k < TT; k += 512) {
        float4 t4 = ((const float4*)targs)[(size_t)b * TT + k];
        qsh[k] = make_float2(t4.x, t4.y);
    }
    for (int k = tid; k < 7 * TT; k += 512) ((float*)mbox)[k] = FINF;

    float px0, py0, px1, py1;
    {
        const int row0 = w * 128 + 2 * lane;
        float4 pv = ((const float4*)preds)[(size_t)b * TT + row0];
        px0 = pv.x; py0 = pv.y;
        float4 pw = ((const float4*)preds)[(size_t)b * TT + row0 + 1];
        px1 = pw.x; py1 = pw.y;
    }
    __syncthreads();

    const float* src = (w > 0) ? mbox[w - 1] : nullptr;
    float*       dst = (w < 7) ? mbox[w]     : nullptr;

    float cur0 = FINF, cur1 = FINF, uprev = FINF, ucur = FINF;
    unsigned au0 = 0, ad0 = 0, au1 = 0, ad1 = 0;
    unsigned pau0 = 0, pad0 = 0, pau1 = 0, pad1 = 0;
    int pT = -1;                             // pending (deferred) dirs window

    const int bi  = 2 * w + (lane >> 5);     // 64-row band index (within batch)
    const int rr0 = 2 * (lane & 31);         // row within band
    const bool is63 = (lane == 63);

    for (int G = 0; G < NPH; ++G) {
        // ---- deferred dirs store for the previous window (post-barrier) ----
        if (pT >= 0) {
            const size_t base = (size_t)((b * 16 + bi) * NW + pT) * 64 + rr0;
            *(uint4*)&dirs[base] =
                make_uint4(__builtin_bitreverse32(pau0), __builtin_bitreverse32(pad0),
                           __builtin_bitreverse32(pau1), __builtin_bitreverse32(pad1));
            pT = -1;
        }
        const int T = G - 3 * w;             // wave-uniform window index
        if ((unsigned)T < (unsigned)NW) {
            // ---- hoisted loads: whole window's boundary + q, one batch ----
            float bnd[33];
#pragma unroll
            for (int k = 0; k < 33; ++k) bnd[k] = FINF;
            if (w > 0) {
#pragma unroll
                for (int k = 0; k < 33; ++k) {
                    const int c = 32 * T + k;
                    if (c < TT) bnd[k] = src[c];
                }
            }
            if (T == 0) ucur = bnd[0];   // first-step u: src[0] (w>0) / FINF
            float qx[32], qy[32];
#pragma unroll
            for (int k = 0; k < 32; ++k) {
                float2 v = qsh[(32 * T + k - lane) & (TT - 1)];
                qx[k] = v.x; qy[k] = v.y;
            }
            float bq[32];
            auto body = [&](auto actc) {
                constexpr bool ACT = decltype(actc)::value;
#pragma unroll
                for (int k2 = 0; k2 < 32; ++k2) {
                    const int s = 32 * T + k2;
                    const float dx0 = px0 - qx[k2], dy0 = py0 - qy[k2];
                    const float d0 = __builtin_amdgcn_sqrtf(dx0 * dx0 + dy0 * dy0);
                    const float dx1 = px1 - qx[k2], dy1 = py1 - qy[k2];
                    const float d1 = __builtin_amdgcn_sqrtf(dx1 * dx1 + dy1 * dy1);

                    const float u = ucur;
                    // row0: cd=uprev, cu=u, cl=cur0  (min3 + eq-argmin)
                    float ba0 = fminf(fminf(u, cur0), uprev);
                    const unsigned bd0 = (uprev == ba0) ? 1u : 0u;
                    const unsigned bu0 = ((u <= cur0) ? 1u : 0u) | bd0;
                    if constexpr (ACT) ba0 = (ba0 > 9e29f) ? 0.0f : ba0;
                    const float v0 = d0 + ba0;
                    // row1: cd=cur0, cu=v0, cl=cur1
                    const float ba1 = fminf(fminf(v0, cur1), cur0);
                    const unsigned bd1 = (cur0 == ba1) ? 1u : 0u;
                    const unsigned bu1 = ((v0 <= cur1) ? 1u : 0u) | bd1;
                    const float v1 = d1 + ba1;

                    au0 = au0 + au0 + bu0;  ad0 = ad0 + ad0 + bd0;
                    au1 = au1 + au1 + bu1;  ad1 = ad1 + ad1 + bd1;

                    if constexpr (ACT) {
                        const bool act = (lane <= s);
                        cur0 = act ? v0 : cur0;
                        cur1 = act ? v1 : cur1;
                    } else {
                        cur0 = v0; cur1 = v1;
                    }
                    uprev = u;
                    bq[k2] = cur1;
                    // next step's u: lane0 <- boundary col s+1, lanes>0 <- shift
                    ucur = dpp_shr1_old(bnd[k2 + 1], cur1);
                }
            };
            if (T < 2) body(BoolC<true>{}); else body(BoolC<false>{});

            // batched boundary publish (plain LDS; closing barrier orders it)
            if (is63 && w < 7) {
#pragma unroll
                for (int k2 = 0; k2 < 32; ++k2) {
                    const int c = 32 * T + k2 - 63;
                    if ((unsigned)c < 1024u) dst[c] = bq[k2];
                }
            }
            pau0 = au0; pad0 = ad0; pau1 = au1; pad1 = ad1; pT = T;
            au0 = ad0 = au1 = ad1 = 0u;
        }
        __syncthreads();   // phase barrier (uniform across the block)
    }
    // flush the final window's dirs
    if (pT >= 0) {
        const size_t base = (size_t)((b * 16 + bi) * NW + pT) * 64 + rr0;
        *(uint4*)&dirs[base] =
            make_uint4(__builtin_bitreverse32(pau0), __builtin_bitreverse32(pad0),
                       __builtin_bitreverse32(pau1), __builtin_bitreverse32(pad1));
    }
}

// ---------------- K2: exit-only per-band walk (no loss) ----------------
__global__ __launch_bounds__(1024) void dtw_exits(
    const uint2* __restrict__ dirs,
    unsigned short* __restrict__ exitc)
{
    __shared__ uint2 raw[NW * 64];
    __shared__ unsigned nebit[64][32];
    __shared__ unsigned dgbit[64][32];

    const int tid = threadIdx.x;
    const int b = blockIdx.x >> 4, bi = blockIdx.x & 15;

    for (int i = tid; i < NW * 64; i += 1024)
        raw[i] = dirs[(size_t)(b * 16 + bi) * (NW * 64) + i];
    __syncthreads();
    for (int i = tid; i < 64 * 32; i += 1024) {
        const int rr = i >> 5, u = i & 31;
        const int o  = ((bi & 1) << 5) + (rr >> 1);   // slope-1, 2 rows/lane
        const int T0 = u + (o >> 5), sh = o & 31;
        uint2 A  = raw[T0 * 64 + rr];
        uint2 Bv = raw[(T0 + 1) * 64 + rr];
        nebit[rr][u] = sh ? ((A.x >> sh) | (Bv.x << (32 - sh))) : A.x;
        dgbit[rr][u] = sh ? ((A.y >> sh) | (Bv.y << (32 - sh))) : A.y;
    }
    __syncthreads();

    int j = tid;
    for (int rr = 63; rr >= 0; --rr) {
        if (bi == 0 && rr == 0) { j = 0; break; }
        int u = j >> 5, m = j & 31;
        unsigned wv = nebit[rr][u] << (31 - m);
        while (wv == 0u && u > 0) { --u; wv = nebit[rr][u]; m = 31; }
        const int j2 = (wv == 0u) ? 0 : ((u << 5) + m - __builtin_clz(wv));
        const int diag = (int)((dgbit[rr][j2 >> 5] >> (j2 & 31)) & 1u);
        j = j2 - diag;
        if (j < 0) j = 0;   // safety net (unreachable on correct dirs)
    }
    exitc[((size_t)(b * 16 + bi) << 10) + tid] = (unsigned short)j;
}

// ---------------- K3: loss replay (stitch folded in) ----------------
__global__ __launch_bounds__(64) void dtw_loss(
    const float* __restrict__ preds,
    const float* __restrict__ targs,
    const float* __restrict__ subcoef,
    const uint2* __restrict__ dirs,
    const unsigned short* __restrict__ exitc,
    float* __restrict__ out)
{
    __shared__ uint2 raw[NW * 64];
    __shared__ unsigned nebit[64][32];
    __shared__ unsigned dgbit[64][32];
    __shared__ float2 qsh[TT];
    __shared__ float2 psh[64];
    __shared__ unsigned recs[160];

    const int lane = threadIdx.x;
    const int b = blockIdx.x >> 4, bi = blockIdx.x & 15;

    for (int i = lane; i < NW * 64; i += 64)
        raw[i] = dirs[(size_t)(b * 16 + bi) * (NW * 64) + i];
    for (int k = lane; k < TT; k += 64) {
        float4 t4 = ((const float4*)targs)[(size_t)b * TT + k];
        qsh[k] = make_float2(t4.x, t4.y);
    }
    {
        float4 p4 = ((const float4*)preds)[(size_t)b * TT + bi * 64 + lane];
        psh[lane] = make_float2(p4.x, p4.y);
    }
    __syncthreads();
    for (int i = lane; i < 64 * 32; i += 64) {
        const int rr = i >> 5, u = i & 31;
        const int o  = ((bi & 1) << 5) + (rr >> 1);   // slope-1, 2 rows/lane
        const int T0 = u + (o >> 5), sh = o & 31;
        uint2 A  = raw[T0 * 64 + rr];
        uint2 Bv = raw[(T0 + 1) * 64 + rr];
        nebit[rr][u] = sh ? ((A.x >> sh) | (Bv.x << (32 - sh))) : A.x;
        dgbit[rr][u] = sh ? ((A.y >> sh) | (Bv.y << (32 - sh))) : A.y;
    }

    // entry col for this band: fold of exitc over bands 15..bi+1 (K3 inlined;
    // broadcast same-address loads, <=15 dependent L2 hits)
    int j = TT - 1;
    for (int k = 15; k > bi; --k)
        j = exitc[((size_t)(b * 16 + k) << 10) + j];
    __syncthreads();

    // wave-redundant replay; lane 0 records <=32-col span chunks
    int nrec = 0;
    for (int rr = 63; rr >= 0; --rr) {
        int j2;
        if (bi == 0 && rr == 0) j2 = 0;
        else {
            int u = j >> 5, m = j & 31;
            unsigned wv = nebit[rr][u] << (31 - m);
            while (wv == 0u && u > 0) { --u; wv = nebit[rr][u]; m = 31; }
            j2 = (wv == 0u) ? 0 : ((u << 5) + m - __builtin_clz(wv));
        }
        int c = j;
        for (;;) {
            int cl = (c - 31 > j2) ? (c - 31) : j2;
            if (lane == 0)
                recs[nrec] = ((unsigned)rr << 20) | ((unsigned)cl << 10) | (unsigned)c;
            ++nrec;
            if (cl == j2) break;
            c = cl - 1;
        }
        if (bi == 0 && rr == 0) j = 0;
        else {
            const int diag = (int)((dgbit[rr][j2 >> 5] >> (j2 & 31)) & 1u);
            j = j2 - diag;
            if (j < 0) j = 0;   // safety net (unreachable on correct dirs)
        }
    }
    __syncthreads();

    const float sc0 = subcoef[0], sc1 = subcoef[1];
    float acc = 0.0f;
    for (int k = lane; k < nrec; k += 64) {
        unsigned rec = recs[k];
        int rr = (int)(rec >> 20), cl = (int)((rec >> 10) & 1023u), ch = (int)(rec & 1023u);
        float2 p = psh[rr];
        for (int c = cl; c <= ch; ++c) {
            float2 q = qsh[c];
            acc += fabsf(p.x - q.x) * sc0 + fabsf(p.y - q.y) * sc1;
        }
    }
    for (int o = 32; o; o >>= 1) acc += __shfl_down(acc, o);
    if (lane == 0) atomicAdd(out, acc);
}

extern "C" void kernel_launch(void* const* d_in, const int* in_sizes, int n_in,
                              void* d_out, int out_size, void* d_ws, size_t ws_size,
                              hipStream_t stream)
{
    const float* preds   = (const float*)d_in[0];
    const float* targs   = (const float*)d_in[1];
    const float* subcoef = (const float*)d_in[2];
    float* out = (float*)d_out;

    const int B = in_sizes[0] / (TT * 4);

    const size_t dirsBytes = (size_t)B * 16 * NW * 64 * sizeof(uint2);        // ~17.8 MB
    uint2* dirs = (uint2*)d_ws;
    unsigned short* exitc = (unsigned short*)((char*)d_ws + dirsBytes);       // 2 MB

    hipMemsetAsync(out, 0, sizeof(float), stream);
    dtw_forward<<<dim3(B * 4), dim3(512), 0, stream>>>(preds, targs, dirs);
    dtw_exits<<<dim3(B * 16), dim3(1024), 0, stream>>>(dirs, exitc);
    dtw_loss<<<dim3(B * 16), dim3(64), 0, stream>>>(preds, targs, subcoef, dirs, exitc, out);
}